// Round 3
// baseline (7295.499 us; speedup 1.0000x reference)
//
#include <hip/hip_runtime.h>
#include <stdint.h>

#define B_ 4
#define T_ 2048
#define C_ 768
#define H_ 12
#define D_ 64
#define BT_ (B_*T_)
#define C3_ (3*C_)
#define FMIN_ (-3.402823466e38f)

typedef __attribute__((ext_vector_type(8))) short short8;

__device__ __forceinline__ float bf2f(unsigned short u) {
    union { unsigned int i; float f; } v; v.i = ((unsigned int)u) << 16; return v.f;
}
__device__ __forceinline__ unsigned short f2bf(float f) {
    union { float ff; unsigned int i; } v; v.ff = f;
    unsigned int r = v.i + 0x7fffu + ((v.i >> 16) & 1u);
    return (unsigned short)(r >> 16);
}
// generic loader: isbf ? bf16 : f32
__device__ __forceinline__ float ldf(const void* p, size_t i, int isbf) {
    return isbf ? bf2f(((const unsigned short*)p)[i]) : ((const float*)p)[i];
}

// ---------------- dtype detection, per tensor ----------------
// flags[0..4]: 1 if tensor {x,wqkv,bqkv,wproj,bproj} is bf16, 0 if f32
// flags[5]: mask mode: 1=int32, 2=f32, 0=uint8/bool
// flags[6]: constant 1 (AO operand of GEMM1 is always bf16)
__global__ void k_detect(const void* x, const void* wqkv, const void* bqkv,
                         const void* wproj, const void* bproj, const void* mask,
                         int* flags) {
    __shared__ int cnt[8];
    int tid = threadIdx.x;
    if (tid < 8) cnt[tid] = 0;
    __syncthreads();
    const void* ptrs[5] = {x, wqkv, bqkv, wproj, bproj};
#pragma unroll
    for (int t = 0; t < 5; ++t) {
        // even 16-bit words: bf16 values (exponent clustered ~118..132) vs
        // f32 low-mantissa halves (bits uniform -> ~16% in range)
        unsigned short u = ((const unsigned short*)ptrs[t])[2 * tid];
        int e = (u >> 7) & 0xff;
        if (e >= 100 && e <= 140) atomicAdd(&cnt[t], 1);
    }
    if (tid < 64) {
        unsigned int d = ((const unsigned int*)mask)[tid];
        if (d <= 1u) atomicAdd(&cnt[5], 1);                      // int32 0/1
        if (d == 0u || d == 0x3f800000u) atomicAdd(&cnt[6], 1);  // f32 0.0/1.0
    }
    __syncthreads();
    if (tid < 5) flags[tid] = (cnt[tid] >= 128) ? 1 : 0;
    if (tid == 5) flags[5] = (cnt[5] == 64) ? 1 : ((cnt[6] == 64) ? 2 : 0);
    if (tid == 6) flags[6] = 1;
}

// ---------------- mask -> additive f32 bias per (b, key) ----------------
__global__ void k_mask(const void* mask, float* maskF, const int* flags) {
    int i = blockIdx.x * 256 + threadIdx.x;
    if (i >= BT_) return;
    int mm = flags[5];
    int mv;
    if (mm == 1)      mv = ((const int*)mask)[i] != 0;
    else if (mm == 2) mv = ((const float*)mask)[i] != 0.0f;
    else              mv = ((const unsigned char*)mask)[i] != 0;
    maskF[i] = mv ? FMIN_ : 0.0f;   // True = padded key -> -FLT_MAX bias
}

// ---------------- simple tiled f32 GEMM: C = A[M][K] @ B[K][N] + bias ----------------
// EPI 0: scatter into Q([B,H,T,D], *0.125), K([B,H,T,D]), V([B,H,T,D]), all bf16
// EPI 1: f32 [M][N] into d_out
template<int EPI>
__global__ __launch_bounds__(256) void k_gemm_s(
        const void* __restrict__ A, const void* __restrict__ Bw,
        const void* __restrict__ bias, const int* __restrict__ flags,
        int fAi, int fBi, int fbi,
        void* __restrict__ out0, unsigned short* __restrict__ out1,
        unsigned short* __restrict__ out2,
        int M, int N, int K) {
    __shared__ float As[16][65];   // [k][m]
    __shared__ float Bs[16][65];   // [k][n]
    const int tid = threadIdx.x;
    const int tx = tid & 15, ty = tid >> 4;
    const int n0 = blockIdx.x * 64, m0 = blockIdx.y * 64;
    const int fA = flags[fAi], fB = flags[fBi], fb = flags[fbi];
    float acc[4][4] = {};
    for (int k0 = 0; k0 < K; k0 += 16) {
#pragma unroll
        for (int q = 0; q < 4; ++q) {
            int e = tid + q * 256;
            int ar = e >> 4, ac = e & 15;       // A: 64 rows x 16 k
            As[ac][ar] = ldf(A, (size_t)(m0 + ar) * K + k0 + ac, fA);
            int bc = e >> 6, br = e & 63;       // B: 16 k x 64 cols
            Bs[bc][br] = ldf(Bw, (size_t)(k0 + bc) * N + n0 + br, fB);
        }
        __syncthreads();
#pragma unroll
        for (int kk = 0; kk < 16; ++kk) {
            float a[4], b[4];
#pragma unroll
            for (int i = 0; i < 4; ++i) a[i] = As[kk][ty * 4 + i];
#pragma unroll
            for (int j = 0; j < 4; ++j) b[j] = Bs[kk][tx * 4 + j];
#pragma unroll
            for (int i = 0; i < 4; ++i)
#pragma unroll
                for (int j = 0; j < 4; ++j)
                    acc[i][j] += a[i] * b[j];
        }
        __syncthreads();
    }
#pragma unroll
    for (int i = 0; i < 4; ++i)
#pragma unroll
        for (int j = 0; j < 4; ++j) {
            int row = m0 + ty * 4 + i;
            int col = n0 + tx * 4 + j;
            float v = acc[i][j] + ldf(bias, col, fb);
            if (EPI == 0) {
                int seg = col / C_;            // 0=q 1=k 2=v
                int c = col - seg * C_;
                int h = c >> 6, d = c & 63;
                int b = row >> 11, t = row & (T_ - 1);
                size_t idx = (((size_t)b * H_ + h) * T_ + t) * D_ + d;
                if (seg == 0)      ((unsigned short*)out0)[idx] = f2bf(v * 0.125f);  // q/sqrt(64)
                else if (seg == 1) out1[idx] = f2bf(v);
                else               out2[idx] = f2bf(v);
            } else {
                ((float*)out0)[(size_t)row * N + col] = v;   // f32 final output
            }
        }
}

// ---------------- simple attention: one block per (b,h,q-row) ----------------
// Q pre-scaled by 1/8. Q,K,V all [B,H,T,D] bf16. Output AO [B,T,C] bf16.
__global__ __launch_bounds__(256) void k_attn_s(
        const unsigned short* __restrict__ Q, const unsigned short* __restrict__ K,
        const unsigned short* __restrict__ V, const float* __restrict__ maskF,
        unsigned short* __restrict__ AO) {
    __shared__ float qs[64];
    __shared__ float ps[T_];
    __shared__ float red[256];
    __shared__ float osum[4][64];
    const int tid = threadIdx.x;
    const int q = blockIdx.x & (T_ - 1);
    const int bh = blockIdx.x >> 11;
    const int b = bh / H_, h = bh - b * H_;
    const unsigned short* Qr = Q + ((size_t)bh * T_ + q) * D_;
    const unsigned short* Kb = K + (size_t)bh * T_ * D_;
    const unsigned short* Vb = V + (size_t)bh * T_ * D_;

    if (tid < 64) qs[tid] = bf2f(Qr[tid]);
    __syncthreads();

    // scores for keys j = tid + jj*256 (8 per thread)
    float s[8];
    float mloc = -INFINITY;
#pragma unroll
    for (int jj = 0; jj < 8; ++jj) {
        int j = tid + jj * 256;
        const unsigned short* Kr = Kb + (size_t)j * D_;
        float acc = 0.0f;
#pragma unroll
        for (int d8 = 0; d8 < 8; ++d8) {
            short8 kv = *(const short8*)&Kr[d8 * 8];
#pragma unroll
            for (int e = 0; e < 8; ++e)
                acc += qs[d8 * 8 + e] * bf2f((unsigned short)kv[e]);
        }
        acc += maskF[b * T_ + j];
        s[jj] = acc;
        mloc = fmaxf(mloc, acc);
    }
    // block max
    red[tid] = mloc;
    __syncthreads();
    for (int st = 128; st > 0; st >>= 1) {
        if (tid < st) red[tid] = fmaxf(red[tid], red[tid + st]);
        __syncthreads();
    }
    float m = red[0];
    __syncthreads();
    // exp + block sum
    float lloc = 0.0f;
#pragma unroll
    for (int jj = 0; jj < 8; ++jj) {
        float p = __expf(s[jj] - m);
        ps[tid + jj * 256] = p;
        lloc += p;
    }
    red[tid] = lloc;
    __syncthreads();
    for (int st = 128; st > 0; st >>= 1) {
        if (tid < st) red[tid] += red[tid + st];
        __syncthreads();
    }
    float inv = 1.0f / red[0];
    __syncthreads();
    // PV: group g of 64 threads handles 512 keys; thread owns dim d
    const int d = tid & 63, g = tid >> 6;
    float acc = 0.0f;
#pragma unroll 4
    for (int jj = 0; jj < 512; ++jj) {
        int j = g * 512 + jj;
        acc += ps[j] * bf2f(Vb[(size_t)j * D_ + d]);
    }
    osum[g][d] = acc;
    __syncthreads();
    if (g == 0) {
        float o = (osum[0][d] + osum[1][d] + osum[2][d] + osum[3][d]) * inv;
        AO[((size_t)b * T_ + q) * C_ + h * 64 + d] = f2bf(o);
    }
}

extern "C" void kernel_launch(void* const* d_in, const int* in_sizes, int n_in,
                              void* d_out, int out_size, void* d_ws, size_t ws_size,
                              hipStream_t stream) {
    const void* x     = d_in[0];
    const void* mask  = d_in[1];
    const void* wqkv  = d_in[2];
    const void* bqkv  = d_in[3];
    const void* wproj = d_in[4];
    const void* bproj = d_in[5];

    char* ws = (char*)d_ws;
    size_t off = 0;
    auto alloc = [&](size_t bytes) -> void* {
        void* p = ws + off;
        off = (off + bytes + 255) & ~(size_t)255;
        return p;
    };
    int* flags         = (int*)alloc(256);
    float* maskF       = (float*)alloc((size_t)BT_ * 4);
    unsigned short* Qs = (unsigned short*)alloc((size_t)B_*H_*T_*D_ * 2);
    unsigned short* Ks = (unsigned short*)alloc((size_t)B_*H_*T_*D_ * 2);
    unsigned short* Vs = (unsigned short*)alloc((size_t)B_*H_*T_*D_ * 2);
    unsigned short* AO = (unsigned short*)alloc((size_t)BT_ * C_ * 2);

    k_detect<<<1, 256, 0, stream>>>(x, wqkv, bqkv, wproj, bproj, mask, flags);
    k_mask<<<(BT_ + 255)/256, 256, 0, stream>>>(mask, maskF, flags);

    // QKV projection: x[8192][768] @ Wqkv[768][2304] + bqkv -> scatter Q,K,V
    k_gemm_s<0><<<dim3(C3_/64, BT_/64), 256, 0, stream>>>(
        x, wqkv, bqkv, flags, /*fA=*/0, /*fB=*/1, /*fb=*/2,
        Qs, Ks, Vs, BT_, C3_, C_);

    // attention
    k_attn_s<<<B_*H_*T_, 256, 0, stream>>>(Qs, Ks, Vs, maskF, AO);

    // output projection: AO[8192][768](bf16) @ Wproj[768][768] + bproj -> d_out f32
    k_gemm_s<1><<<dim3(C_/64, BT_/64), 256, 0, stream>>>(
        AO, wproj, bproj, flags, /*fA=*/6, /*fB=*/3, /*fb=*/4,
        d_out, nullptr, nullptr, BT_, C_, C_);
}

// Round 4
// 265.934 us; speedup vs baseline: 27.4335x; 27.4335x over previous
//
#include <hip/hip_runtime.h>
#include <stdint.h>

#define B_ 4
#define T_ 2048
#define C_ 768
#define H_ 12
#define D_ 64
#define BT_ (B_*T_)
#define C3_ (3*C_)
#define FMIN_ (-3.402823466e38f)

typedef __attribute__((ext_vector_type(8))) short short8;
typedef __attribute__((ext_vector_type(4))) float f32x4;

__device__ __forceinline__ float bf2f(unsigned short u) {
    union { unsigned int i; float f; } v; v.i = ((unsigned int)u) << 16; return v.f;
}
__device__ __forceinline__ unsigned short f2bf(float f) {
    union { float ff; unsigned int i; } v; v.ff = f;
    unsigned int r = v.i + 0x7fffu + ((v.i >> 16) & 1u);
    return (unsigned short)(r >> 16);
}
__device__ __forceinline__ float ldf(const void* p, size_t i, int isbf) {
    return isbf ? bf2f(((const unsigned short*)p)[i]) : ((const float*)p)[i];
}

// ---------------- dtype detection, per tensor ----------------
// flags[0..4]: 1 if {x,wqkv,bqkv,wproj,bproj} is bf16, 0 if f32
// flags[5]: mask mode: 1=int32, 2=f32, 0=uint8/bool
__global__ void k_detect(const void* x, const void* wqkv, const void* bqkv,
                         const void* wproj, const void* bproj, const void* mask,
                         int* flags) {
    __shared__ int cnt[8];
    int tid = threadIdx.x;
    if (tid < 8) cnt[tid] = 0;
    __syncthreads();
    const void* ptrs[5] = {x, wqkv, bqkv, wproj, bproj};
#pragma unroll
    for (int t = 0; t < 5; ++t) {
        unsigned short u = ((const unsigned short*)ptrs[t])[2 * tid];
        int e = (u >> 7) & 0xff;
        if (e >= 100 && e <= 140) atomicAdd(&cnt[t], 1);
    }
    if (tid < 64) {
        unsigned int d = ((const unsigned int*)mask)[tid];
        if (d <= 1u) atomicAdd(&cnt[5], 1);
        if (d == 0u || d == 0x3f800000u) atomicAdd(&cnt[6], 1);
    }
    __syncthreads();
    if (tid < 5) flags[tid] = (cnt[tid] >= 128) ? 1 : 0;
    if (tid == 5) flags[5] = (cnt[5] == 64) ? 1 : ((cnt[6] == 64) ? 2 : 0);
}

// ---------------- canonicalize x -> bf16 ----------------
__global__ void k_canon_x(const void* x, unsigned short* xb, const int* flags) {
    const int n8 = BT_ * C_ / 8;
    int i = blockIdx.x * blockDim.x + threadIdx.x;
    if (i >= n8) return;
    if (flags[0]) {
        ((int4*)xb)[i] = ((const int4*)x)[i];
    } else {
        const float4* xf = (const float4*)x;
        float4 a = xf[2*i], b = xf[2*i+1];
        short8 o;
        o[0]=(short)f2bf(a.x); o[1]=(short)f2bf(a.y); o[2]=(short)f2bf(a.z); o[3]=(short)f2bf(a.w);
        o[4]=(short)f2bf(b.x); o[5]=(short)f2bf(b.y); o[6]=(short)f2bf(b.z); o[7]=(short)f2bf(b.w);
        *(short8*)&xb[8*i] = o;
    }
}

// ---------------- transpose weight [K][N] -> bf16 [N][K] ----------------
__global__ void k_canon_wT(const void* src, unsigned short* dst, const int* flags,
                           int fidx, int K, int N) {
    __shared__ float tile[32][33];
    int mode = flags[fidx];
    int n0 = blockIdx.x * 32, k0 = blockIdx.y * 32;
    int tx = threadIdx.x & 31, ty = threadIdx.x >> 5;
    for (int r = ty; r < 32; r += 8) {
        size_t idx = (size_t)(k0 + r) * N + (n0 + tx);
        tile[r][tx] = mode ? bf2f(((const unsigned short*)src)[idx])
                           : ((const float*)src)[idx];
    }
    __syncthreads();
    for (int r = ty; r < 32; r += 8) {
        dst[(size_t)(n0 + r) * K + k0 + tx] = f2bf(tile[tx][r]);
    }
}

// ---------------- biases (f32) + mask bias ----------------
__global__ void k_canon_small(const void* bqkv, const void* bproj, const void* mask,
                              float* bqkvF, float* bprojF, float* maskF, const int* flags) {
    int i = blockIdx.x * blockDim.x + threadIdx.x;
    if (i < C3_) bqkvF[i] = ldf(bqkv, i, flags[2]);
    if (i < C_)  bprojF[i] = ldf(bproj, i, flags[4]);
    if (i < BT_) {
        int mm = flags[5];
        int mv;
        if (mm == 1)      mv = ((const int*)mask)[i] != 0;
        else if (mm == 2) mv = ((const float*)mask)[i] != 0.0f;
        else              mv = ((const unsigned char*)mask)[i] != 0;
        maskF[i] = mv ? FMIN_ : 0.0f;
    }
}

// ---------------- bf16 MFMA GEMM: C = A[M][K] * Bt[N][K]^T + bias ----------------
// EPI 0: scatter into Q([B,H,T,D], *0.125), K([B,H,T,D]), V^T([B,H,D,T]), bf16
// EPI 1: f32 [M][N] into d_out
template<int EPI>
__global__ __launch_bounds__(256) void k_gemm(
        const unsigned short* __restrict__ A, const unsigned short* __restrict__ Bt,
        const float* __restrict__ bias,
        void* __restrict__ out0, unsigned short* __restrict__ out1,
        unsigned short* __restrict__ out2,
        int M, int N, int K) {
    __shared__ __align__(16) unsigned short la[128*72];
    __shared__ __align__(16) unsigned short lb[128*72];
    const int tid = threadIdx.x;
    const int w = tid >> 6, lane = tid & 63, lr = lane & 15, lg = lane >> 4;
    const int wm = (w >> 1) * 64, wn = (w & 1) * 64;
    const int n0 = blockIdx.x * 128, m0 = blockIdx.y * 128;
    f32x4 acc[4][4] = {};
    for (int k0 = 0; k0 < K; k0 += 64) {
#pragma unroll
        for (int c = 0; c < 4; ++c) {
            int idx = tid + c * 256;
            int row = idx >> 3, c8 = (idx & 7) * 8;
            *(short8*)&la[row*72 + c8] = *(const short8*)&A[(size_t)(m0+row)*K + k0 + c8];
            *(short8*)&lb[row*72 + c8] = *(const short8*)&Bt[(size_t)(n0+row)*K + k0 + c8];
        }
        __syncthreads();
#pragma unroll
        for (int ks = 0; ks < 64; ks += 32) {
            short8 af[4], bfr[4];
#pragma unroll
            for (int i = 0; i < 4; ++i)
                af[i] = *(const short8*)&la[(wm + i*16 + lr)*72 + ks + lg*8];
#pragma unroll
            for (int j = 0; j < 4; ++j)
                bfr[j] = *(const short8*)&lb[(wn + j*16 + lr)*72 + ks + lg*8];
#pragma unroll
            for (int i = 0; i < 4; ++i)
#pragma unroll
                for (int j = 0; j < 4; ++j)
                    acc[i][j] = __builtin_amdgcn_mfma_f32_16x16x32_bf16(af[i], bfr[j], acc[i][j], 0, 0, 0);
        }
        __syncthreads();
    }
#pragma unroll
    for (int i = 0; i < 4; ++i)
#pragma unroll
        for (int j = 0; j < 4; ++j)
#pragma unroll
            for (int r = 0; r < 4; ++r) {
                int row = m0 + wm + i*16 + lg*4 + r;
                int col = n0 + wn + j*16 + lr;
                float v = acc[i][j][r] + bias[col];
                if (EPI == 0) {
                    int seg = col / C_;
                    int c = col - seg * C_;
                    int h = c >> 6, d = c & 63;
                    int b = row >> 11, t = row & (T_ - 1);
                    if (seg == 0)      ((unsigned short*)out0)[(((size_t)b*H_ + h)*T_ + t)*D_ + d] = f2bf(v * 0.125f);
                    else if (seg == 1) out1[(((size_t)b*H_ + h)*T_ + t)*D_ + d] = f2bf(v);
                    else               out2[(((size_t)b*H_ + h)*D_ + d)*T_ + t] = f2bf(v);
                } else {
                    ((float*)out0)[(size_t)row * N + col] = v;
                }
            }
}

// ---------------- flash attention ----------------
// Q[B,H,T,D] (pre-scaled 1/8), K[B,H,T,D], V^T[B,H,D,T], all bf16.
// Block = 4 waves; wave w owns 32 q rows. KVBLK=64.
__global__ __launch_bounds__(256) void k_attn(
        const unsigned short* __restrict__ Q, const unsigned short* __restrict__ Kt,
        const unsigned short* __restrict__ Vt, const float* __restrict__ maskF,
        unsigned short* __restrict__ AO) {
    __shared__ __align__(16) unsigned short lk[64*72];
    __shared__ __align__(16) unsigned short lv[64*72];
    __shared__ __align__(16) unsigned short lp[4][32*72];
    __shared__ float lmb[64];
    const int tid = threadIdx.x;
    const int w = tid >> 6, lane = tid & 63, lr = lane & 15, lg = lane >> 4;
    const int bh = blockIdx.x >> 4, qt = blockIdx.x & 15;
    const int b = bh / H_, h = bh - b * H_;
    const int qbase = qt * 128 + w * 32;
    const unsigned short* Qb = Q  + (size_t)bh * T_ * D_;
    const unsigned short* Kb = Kt + (size_t)bh * T_ * D_;
    const unsigned short* Vb = Vt + (size_t)bh * D_ * T_;

    short8 qf[2][2];
#pragma unroll
    for (int mf = 0; mf < 2; ++mf)
#pragma unroll
        for (int ks = 0; ks < 2; ++ks)
            qf[mf][ks] = *(const short8*)&Qb[(size_t)(qbase + mf*16 + lr) * D_ + ks*32 + lg*8];

    f32x4 o[2][4] = {};
    float m[2][4], l[2][4];
#pragma unroll
    for (int mf = 0; mf < 2; ++mf)
#pragma unroll
        for (int r = 0; r < 4; ++r) { m[mf][r] = -INFINITY; l[mf][r] = 0.0f; }

    for (int kt = 0; kt < T_; kt += 64) {
#pragma unroll
        for (int c = 0; c < 2; ++c) {
            int idx = tid + c * 256;
            int row = idx >> 3, c8 = (idx & 7) * 8;
            *(short8*)&lk[row*72 + c8] = *(const short8*)&Kb[(size_t)(kt + row)*D_ + c8];
            *(short8*)&lv[row*72 + c8] = *(const short8*)&Vb[(size_t)row * T_ + kt + c8];
        }
        if (tid < 64) lmb[tid] = maskF[b*T_ + kt + tid];
        __syncthreads();

        // S = Q K^T  (q rows x 64 keys)
        f32x4 s[2][4] = {};
#pragma unroll
        for (int ks = 0; ks < 2; ++ks) {
            short8 kf[4];
#pragma unroll
            for (int nf = 0; nf < 4; ++nf)
                kf[nf] = *(const short8*)&lk[(nf*16 + lr)*72 + ks*32 + lg*8];
#pragma unroll
            for (int mf = 0; mf < 2; ++mf)
#pragma unroll
                for (int nf = 0; nf < 4; ++nf)
                    s[mf][nf] = __builtin_amdgcn_mfma_f32_16x16x32_bf16(qf[mf][ks], kf[nf], s[mf][nf], 0, 0, 0);
        }
        // mask: padded key -> scores = -FLT_MAX (exact jnp.where semantics)
        float mb[4];
#pragma unroll
        for (int nf = 0; nf < 4; ++nf) mb[nf] = lmb[nf*16 + lr];
#pragma unroll
        for (int mf = 0; mf < 2; ++mf)
#pragma unroll
            for (int nf = 0; nf < 4; ++nf)
                if (mb[nf] != 0.0f) {
#pragma unroll
                    for (int r = 0; r < 4; ++r) s[mf][nf][r] = FMIN_;
                }
        // online softmax (per q row = (mf, lg*4+r); row spread over 16 lanes lr)
#pragma unroll
        for (int mf = 0; mf < 2; ++mf)
#pragma unroll
            for (int r = 0; r < 4; ++r) {
                float tm = fmaxf(fmaxf(s[mf][0][r], s[mf][1][r]), fmaxf(s[mf][2][r], s[mf][3][r]));
#pragma unroll
                for (int off = 1; off < 16; off <<= 1) tm = fmaxf(tm, __shfl_xor(tm, off));
                float mo = m[mf][r];
                float mn = fmaxf(mo, tm);
                float sc = __expf(mo - mn);
                m[mf][r] = mn;
                float ps = 0.0f;
#pragma unroll
                for (int nf = 0; nf < 4; ++nf) {
                    float p = __expf(s[mf][nf][r] - mn);
                    s[mf][nf][r] = p;
                    ps += p;
                }
                l[mf][r] = l[mf][r] * sc + ps;   // lane-partial; reduced at end
#pragma unroll
                for (int dn = 0; dn < 4; ++dn) o[mf][dn][r] *= sc;
            }
        // P -> LDS (relayout to A-fragment), per-wave buffer, in-wave ordering ok
#pragma unroll
        for (int mf = 0; mf < 2; ++mf)
#pragma unroll
            for (int nf = 0; nf < 4; ++nf)
#pragma unroll
                for (int r = 0; r < 4; ++r)
                    lp[w][(mf*16 + lg*4 + r)*72 + nf*16 + lr] = f2bf(s[mf][nf][r]);
        // O += P V
#pragma unroll
        for (int ks = 0; ks < 2; ++ks) {
            short8 pf[2], vf[4];
#pragma unroll
            for (int mf = 0; mf < 2; ++mf)
                pf[mf] = *(const short8*)&lp[w][(mf*16 + lr)*72 + ks*32 + lg*8];
#pragma unroll
            for (int dn = 0; dn < 4; ++dn)
                vf[dn] = *(const short8*)&lv[(dn*16 + lr)*72 + ks*32 + lg*8];
#pragma unroll
            for (int mf = 0; mf < 2; ++mf)
#pragma unroll
                for (int dn = 0; dn < 4; ++dn)
                    o[mf][dn] = __builtin_amdgcn_mfma_f32_16x16x32_bf16(pf[mf], vf[dn], o[mf][dn], 0, 0, 0);
        }
        __syncthreads();
    }
#pragma unroll
    for (int mf = 0; mf < 2; ++mf)
#pragma unroll
        for (int r = 0; r < 4; ++r) {
            float ls = l[mf][r];
#pragma unroll
            for (int off = 1; off < 16; off <<= 1) ls += __shfl_xor(ls, off);
            float inv = 1.0f / ls;
            int row = b*T_ + qbase + mf*16 + lg*4 + r;
#pragma unroll
            for (int dn = 0; dn < 4; ++dn)
                AO[(size_t)row * C_ + h*64 + dn*16 + lr] = f2bf(o[mf][dn][r] * inv);
        }
}

extern "C" void kernel_launch(void* const* d_in, const int* in_sizes, int n_in,
                              void* d_out, int out_size, void* d_ws, size_t ws_size,
                              hipStream_t stream) {
    const void* x     = d_in[0];
    const void* mask  = d_in[1];
    const void* wqkv  = d_in[2];
    const void* bqkv  = d_in[3];
    const void* wproj = d_in[4];
    const void* bproj = d_in[5];

    char* ws = (char*)d_ws;
    size_t off = 0;
    auto alloc = [&](size_t bytes) -> void* {
        void* p = ws + off;
        off = (off + bytes + 255) & ~(size_t)255;
        return p;
    };
    int* flags            = (int*)alloc(256);
    unsigned short* Xb    = (unsigned short*)alloc((size_t)BT_ * C_ * 2);
    unsigned short* WqkvT = (unsigned short*)alloc((size_t)C3_ * C_ * 2);
    unsigned short* WprojT= (unsigned short*)alloc((size_t)C_ * C_ * 2);
    float* bqkvF          = (float*)alloc((size_t)C3_ * 4);
    float* bprojF         = (float*)alloc((size_t)C_ * 4);
    float* maskF          = (float*)alloc((size_t)BT_ * 4);
    unsigned short* Qs    = (unsigned short*)alloc((size_t)B_*H_*T_*D_ * 2);
    unsigned short* Ks    = (unsigned short*)alloc((size_t)B_*H_*T_*D_ * 2);
    unsigned short* Vts   = (unsigned short*)alloc((size_t)B_*H_*T_*D_ * 2);
    unsigned short* AO    = (unsigned short*)alloc((size_t)BT_ * C_ * 2);

    k_detect<<<1, 256, 0, stream>>>(x, wqkv, bqkv, wproj, bproj, mask, flags);
    k_canon_x<<<(BT_*C_/8 + 255)/256, 256, 0, stream>>>(x, Xb, flags);
    k_canon_wT<<<dim3(C3_/32, C_/32), 256, 0, stream>>>(wqkv, WqkvT, flags, 1, C_, C3_);
    k_canon_wT<<<dim3(C_/32, C_/32), 256, 0, stream>>>(wproj, WprojT, flags, 3, C_, C_);
    k_canon_small<<<(BT_ + 255)/256, 256, 0, stream>>>(bqkv, bproj, mask, bqkvF, bprojF, maskF, flags);

    // QKV projection -> Q(,K)(,V^T)
    k_gemm<0><<<dim3(C3_/128, BT_/128), 256, 0, stream>>>(
        Xb, WqkvT, bqkvF, Qs, Ks, Vts, BT_, C3_, C_);
    // flash attention
    k_attn<<<B_*H_*(T_/128), 256, 0, stream>>>(Qs, Ks, Vts, maskF, AO);
    // output projection -> f32 d_out
    k_gemm<1><<<dim3(C_/128, BT_/128), 256, 0, stream>>>(
        AO, WprojT, bprojF, d_out, nullptr, nullptr, BT_, C_, C_);
}

// Round 5
// 215.517 us; speedup vs baseline: 33.8512x; 1.2339x over previous
//
#include <hip/hip_runtime.h>
#include <stdint.h>

#define B_ 4
#define T_ 2048
#define C_ 768
#define H_ 12
#define D_ 64
#define BT_ (B_*T_)
#define C3_ (3*C_)
#define FMIN_ (-3.402823466e38f)

typedef __attribute__((ext_vector_type(8))) short short8;
typedef __attribute__((ext_vector_type(4))) short s16x4;
typedef __attribute__((ext_vector_type(4))) float f32x4;

__device__ __forceinline__ float bf2f(unsigned short u) {
    union { unsigned int i; float f; } v; v.i = ((unsigned int)u) << 16; return v.f;
}
__device__ __forceinline__ unsigned short f2bf(float f) {
    union { float ff; unsigned int i; } v; v.ff = f;
    unsigned int r = v.i + 0x7fffu + ((v.i >> 16) & 1u);
    return (unsigned short)(r >> 16);
}
// packed f32x2 -> bf16x2 (RNE), single HW instr
__device__ __forceinline__ unsigned int cvtpk(float lo, float hi) {
    unsigned int r;
    asm("v_cvt_pk_bf16_f32 %0, %1, %2" : "=v"(r) : "v"(lo), "v"(hi));
    return r;
}
__device__ __forceinline__ float ldf(const void* p, size_t i, int isbf) {
    return isbf ? bf2f(((const unsigned short*)p)[i]) : ((const float*)p)[i];
}

// ---------------- dtype detection, per tensor ----------------
// flags[0..4]: 1 if {x,wqkv,bqkv,wproj,bproj} is bf16, 0 if f32
// flags[5]: mask mode: 1=int32, 2=f32, 0=uint8/bool
__global__ void k_detect(const void* x, const void* wqkv, const void* bqkv,
                         const void* wproj, const void* bproj, const void* mask,
                         int* flags) {
    __shared__ int cnt[8];
    int tid = threadIdx.x;
    if (tid < 8) cnt[tid] = 0;
    __syncthreads();
    const void* ptrs[5] = {x, wqkv, bqkv, wproj, bproj};
#pragma unroll
    for (int t = 0; t < 5; ++t) {
        unsigned short u = ((const unsigned short*)ptrs[t])[2 * tid];
        int e = (u >> 7) & 0xff;
        if (e >= 100 && e <= 140) atomicAdd(&cnt[t], 1);
    }
    if (tid < 64) {
        unsigned int d = ((const unsigned int*)mask)[tid];
        if (d <= 1u) atomicAdd(&cnt[5], 1);
        if (d == 0u || d == 0x3f800000u) atomicAdd(&cnt[6], 1);
    }
    __syncthreads();
    if (tid < 5) flags[tid] = (cnt[tid] >= 128) ? 1 : 0;
    if (tid == 5) flags[5] = (cnt[5] == 64) ? 1 : ((cnt[6] == 64) ? 2 : 0);
}

// ---------------- canonicalize x -> bf16 ----------------
__global__ void k_canon_x(const void* x, unsigned short* xb, const int* flags) {
    const int n8 = BT_ * C_ / 8;
    int i = blockIdx.x * blockDim.x + threadIdx.x;
    if (i >= n8) return;
    if (flags[0]) {
        ((int4*)xb)[i] = ((const int4*)x)[i];
    } else {
        const float4* xf = (const float4*)x;
        float4 a = xf[2*i], b = xf[2*i+1];
        short8 o;
        o[0]=(short)f2bf(a.x); o[1]=(short)f2bf(a.y); o[2]=(short)f2bf(a.z); o[3]=(short)f2bf(a.w);
        o[4]=(short)f2bf(b.x); o[5]=(short)f2bf(b.y); o[6]=(short)f2bf(b.z); o[7]=(short)f2bf(b.w);
        *(short8*)&xb[8*i] = o;
    }
}

// ---------------- transpose weight [K][N] -> bf16 [N][K] ----------------
__global__ void k_canon_wT(const void* src, unsigned short* dst, const int* flags,
                           int fidx, int K, int N) {
    __shared__ float tile[32][33];
    int mode = flags[fidx];
    int n0 = blockIdx.x * 32, k0 = blockIdx.y * 32;
    int tx = threadIdx.x & 31, ty = threadIdx.x >> 5;
    for (int r = ty; r < 32; r += 8) {
        size_t idx = (size_t)(k0 + r) * N + (n0 + tx);
        tile[r][tx] = mode ? bf2f(((const unsigned short*)src)[idx])
                           : ((const float*)src)[idx];
    }
    __syncthreads();
    for (int r = ty; r < 32; r += 8) {
        dst[(size_t)(n0 + r) * K + k0 + tx] = f2bf(tile[tx][r]);
    }
}

// ---------------- biases (f32) + mask bias ----------------
__global__ void k_canon_small(const void* bqkv, const void* bproj, const void* mask,
                              float* bqkvF, float* bprojF, float* maskF, const int* flags) {
    int i = blockIdx.x * blockDim.x + threadIdx.x;
    if (i < C3_) bqkvF[i] = ldf(bqkv, i, flags[2]);
    if (i < C_)  bprojF[i] = ldf(bproj, i, flags[4]);
    if (i < BT_) {
        int mm = flags[5];
        int mv;
        if (mm == 1)      mv = ((const int*)mask)[i] != 0;
        else if (mm == 2) mv = ((const float*)mask)[i] != 0.0f;
        else              mv = ((const unsigned char*)mask)[i] != 0;
        maskF[i] = mv ? FMIN_ : 0.0f;
    }
}

// ---------------- bf16 MFMA GEMM: C = A[M][K] * Bt[N][K]^T + bias ----------------
// EPI 0: scatter into Q([B,H,T,D], *0.125), K([B,H,T,D]), V^T([B,H,D,T]), bf16
// EPI 1: f32 [M][N] into d_out
template<int EPI>
__global__ __launch_bounds__(256) void k_gemm(
        const unsigned short* __restrict__ A, const unsigned short* __restrict__ Bt,
        const float* __restrict__ bias,
        void* __restrict__ out0, unsigned short* __restrict__ out1,
        unsigned short* __restrict__ out2,
        int M, int N, int K) {
    __shared__ __align__(16) unsigned short la[128*72];
    __shared__ __align__(16) unsigned short lb[128*72];
    const int tid = threadIdx.x;
    const int w = tid >> 6, lane = tid & 63, lr = lane & 15, lg = lane >> 4;
    const int wm = (w >> 1) * 64, wn = (w & 1) * 64;
    const int n0 = blockIdx.x * 128, m0 = blockIdx.y * 128;
    f32x4 acc[4][4] = {};
    for (int k0 = 0; k0 < K; k0 += 64) {
#pragma unroll
        for (int c = 0; c < 4; ++c) {
            int idx = tid + c * 256;
            int row = idx >> 3, c8 = (idx & 7) * 8;
            *(short8*)&la[row*72 + c8] = *(const short8*)&A[(size_t)(m0+row)*K + k0 + c8];
            *(short8*)&lb[row*72 + c8] = *(const short8*)&Bt[(size_t)(n0+row)*K + k0 + c8];
        }
        __syncthreads();
#pragma unroll
        for (int ks = 0; ks < 64; ks += 32) {
            short8 af[4], bfr[4];
#pragma unroll
            for (int i = 0; i < 4; ++i)
                af[i] = *(const short8*)&la[(wm + i*16 + lr)*72 + ks + lg*8];
#pragma unroll
            for (int j = 0; j < 4; ++j)
                bfr[j] = *(const short8*)&lb[(wn + j*16 + lr)*72 + ks + lg*8];
#pragma unroll
            for (int i = 0; i < 4; ++i)
#pragma unroll
                for (int j = 0; j < 4; ++j)
                    acc[i][j] = __builtin_amdgcn_mfma_f32_16x16x32_bf16(af[i], bfr[j], acc[i][j], 0, 0, 0);
        }
        __syncthreads();
    }
#pragma unroll
    for (int i = 0; i < 4; ++i)
#pragma unroll
        for (int j = 0; j < 4; ++j)
#pragma unroll
            for (int r = 0; r < 4; ++r) {
                int row = m0 + wm + i*16 + lg*4 + r;
                int col = n0 + wn + j*16 + lr;
                float v = acc[i][j][r] + bias[col];
                if (EPI == 0) {
                    int seg = col / C_;
                    int c = col - seg * C_;
                    int h = c >> 6, d = c & 63;
                    int b = row >> 11, t = row & (T_ - 1);
                    if (seg == 0)      ((unsigned short*)out0)[(((size_t)b*H_ + h)*T_ + t)*D_ + d] = f2bf(v * 0.125f);
                    else if (seg == 1) out1[(((size_t)b*H_ + h)*T_ + t)*D_ + d] = f2bf(v);
                    else               out2[(((size_t)b*H_ + h)*D_ + d)*T_ + t] = f2bf(v);
                } else {
                    ((float*)out0)[(size_t)row * N + col] = v;
                }
            }
}

// ---------------- flash attention, swapped QK^T ----------------
// Q[B,H,T,D] (pre-scaled 1/8), K[B,H,T,D], V^T[B,H,D,T], all bf16.
// Block = 4 waves; wave owns 32 q rows. KVBLK = 64.
// S^T = mfma(A=K, B=Q): lane (lr,lg) holds S[q=qc*16+lr][key=kf*16+lg*4+r]
//   -> softmax reduce = in-lane + shfl_xor(16,32); P stays lane-local.
// PV uses a slot-relabeled contraction: slot (ks, s) <-> key
//   (2ks+((s&7)>>2))*16 + (s>>3)*4 + (s&3), applied to BOTH operands:
//   P packs in-lane (cvt_pk), V reads 2x ds_read_b64 per fragment.
// O accumulates transposed: O^T[d][q], col=q=lr -> rescale lane-uniform.
__global__ __launch_bounds__(256) void k_attn(
        const unsigned short* __restrict__ Q, const unsigned short* __restrict__ Kt,
        const unsigned short* __restrict__ Vt, const float* __restrict__ maskF,
        unsigned short* __restrict__ AO) {
    __shared__ __align__(16) unsigned short lk[64*72];
    __shared__ __align__(16) unsigned short lv[64*72];
    __shared__ __align__(16) float lmb[64];
    const int tid = threadIdx.x;
    const int w = tid >> 6, lane = tid & 63, lr = lane & 15, lg = lane >> 4;
    // bijective XCD swizzle: 768 blocks = 8 XCD x 96; 16 consecutive share one bh's K/V
    const int per = gridDim.x >> 3;
    const int swz = (blockIdx.x & 7) * per + (blockIdx.x >> 3);
    const int bh = swz >> 4, qt = swz & 15;
    const int b = bh / H_, h = bh - b * H_;
    const int qbase = qt * 128 + w * 32;
    const unsigned short* Qb = Q  + (size_t)bh * T_ * D_;
    const unsigned short* Kb = Kt + (size_t)bh * T_ * D_;
    const unsigned short* Vb = Vt + (size_t)bh * D_ * T_;

    // Q as B-operand: lane holds col q=qc*16+lr, k-elems d = dh*32+lg*8..+7
    short8 qf[2][2];
#pragma unroll
    for (int qc = 0; qc < 2; ++qc)
#pragma unroll
        for (int dh = 0; dh < 2; ++dh)
            qf[qc][dh] = *(const short8*)&Qb[(size_t)(qbase + qc*16 + lr) * D_ + dh*32 + lg*8];

    f32x4 ot[4][2] = {};           // O^T[dblk][qc]
    float m[2] = {-INFINITY, -INFINITY}, l[2] = {0.0f, 0.0f};

    for (int kt = 0; kt < T_; kt += 64) {
#pragma unroll
        for (int c = 0; c < 2; ++c) {
            int idx = tid + c * 256;
            int row = idx >> 3, c8 = (idx & 7) * 8;
            *(short8*)&lk[row*72 + c8] = *(const short8*)&Kb[(size_t)(kt + row)*D_ + c8];
            *(short8*)&lv[row*72 + c8] = *(const short8*)&Vb[(size_t)row * T_ + kt + c8];
        }
        if (tid < 64) lmb[tid] = maskF[b*T_ + kt + tid];
        __syncthreads();

        // S^T = K Q^T: st[kf][qc], lane reg r = S[q=qc*16+lr][key=kf*16+lg*4+r]
        f32x4 st[4][2] = {};
#pragma unroll
        for (int dh = 0; dh < 2; ++dh) {
            short8 kfr[4];
#pragma unroll
            for (int kf = 0; kf < 4; ++kf)
                kfr[kf] = *(const short8*)&lk[(kf*16 + lr)*72 + dh*32 + lg*8];
#pragma unroll
            for (int kf = 0; kf < 4; ++kf)
#pragma unroll
                for (int qc = 0; qc < 2; ++qc)
                    st[kf][qc] = __builtin_amdgcn_mfma_f32_16x16x32_bf16(kfr[kf], qf[qc][dh], st[kf][qc], 0, 0, 0);
        }
        // mask: key = kf*16 + lg*4 + r -> float4 per kf
        float4 mb[4];
#pragma unroll
        for (int kf = 0; kf < 4; ++kf) mb[kf] = *(const float4*)&lmb[kf*16 + lg*4];
#pragma unroll
        for (int kf = 0; kf < 4; ++kf) {
            const float mr[4] = {mb[kf].x, mb[kf].y, mb[kf].z, mb[kf].w};
#pragma unroll
            for (int qc = 0; qc < 2; ++qc)
#pragma unroll
                for (int r = 0; r < 4; ++r)
                    if (mr[r] != 0.0f) st[kf][qc][r] = FMIN_;
        }
        // online softmax per qc (row = q = qc*16+lr, spread over 4 lanes lg)
#pragma unroll
        for (int qc = 0; qc < 2; ++qc) {
            float tm = -INFINITY;
#pragma unroll
            for (int kf = 0; kf < 4; ++kf)
#pragma unroll
                for (int r = 0; r < 4; ++r) tm = fmaxf(tm, st[kf][qc][r]);
            tm = fmaxf(tm, __shfl_xor(tm, 16));
            tm = fmaxf(tm, __shfl_xor(tm, 32));
            float mo = m[qc];
            float mn = fmaxf(mo, tm);
            float sc = __expf(mo - mn);
            m[qc] = mn;
            float ps = 0.0f;
#pragma unroll
            for (int kf = 0; kf < 4; ++kf)
#pragma unroll
                for (int r = 0; r < 4; ++r) {
                    float p = __expf(st[kf][qc][r] - mn);
                    st[kf][qc][r] = p;
                    ps += p;
                }
            l[qc] = l[qc] * sc + ps;       // lane-partial over this lane's keys
#pragma unroll
            for (int dblk = 0; dblk < 4; ++dblk) ot[dblk][qc] *= sc;
        }
        // pack P in-lane into relabeled B-fragments: pb[qc][ks]
        union PU { unsigned int u[4]; short8 s; };
        PU pb[2][2];
#pragma unroll
        for (int qc = 0; qc < 2; ++qc)
#pragma unroll
            for (int ks = 0; ks < 2; ++ks) {
                pb[qc][ks].u[0] = cvtpk(st[2*ks][qc][0],   st[2*ks][qc][1]);
                pb[qc][ks].u[1] = cvtpk(st[2*ks][qc][2],   st[2*ks][qc][3]);
                pb[qc][ks].u[2] = cvtpk(st[2*ks+1][qc][0], st[2*ks+1][qc][1]);
                pb[qc][ks].u[3] = cvtpk(st[2*ks+1][qc][2], st[2*ks+1][qc][3]);
            }
        // O^T += V^T P^T with matching slot relabel: A-slot (ks,j):
        //   j=0..3 -> key 32ks+lg*4+j ; j=4..7 -> key 32ks+16+lg*4+(j-4)
#pragma unroll
        for (int ks = 0; ks < 2; ++ks)
#pragma unroll
            for (int dblk = 0; dblk < 4; ++dblk) {
                const int rb = (dblk*16 + lr)*72 + 32*ks + lg*4;
                s16x4 lo = *(const s16x4*)&lv[rb];
                s16x4 hi = *(const s16x4*)&lv[rb + 16];
                short8 va;
                va[0]=lo[0]; va[1]=lo[1]; va[2]=lo[2]; va[3]=lo[3];
                va[4]=hi[0]; va[5]=hi[1]; va[6]=hi[2]; va[7]=hi[3];
#pragma unroll
                for (int qc = 0; qc < 2; ++qc)
                    ot[dblk][qc] = __builtin_amdgcn_mfma_f32_16x16x32_bf16(va, pb[qc][ks].s, ot[dblk][qc], 0, 0, 0);
            }
        __syncthreads();
    }
    // epilogue: reduce l across lg, normalize, store O^T -> AO rows
#pragma unroll
    for (int qc = 0; qc < 2; ++qc) {
        float ls = l[qc];
        ls += __shfl_xor(ls, 16);
        ls += __shfl_xor(ls, 32);
        float inv = 1.0f / ls;
        size_t row = (size_t)b*T_ + qbase + qc*16 + lr;
#pragma unroll
        for (int dblk = 0; dblk < 4; ++dblk) {
            unsigned int w0 = cvtpk(ot[dblk][qc][0]*inv, ot[dblk][qc][1]*inv);
            unsigned int w1 = cvtpk(ot[dblk][qc][2]*inv, ot[dblk][qc][3]*inv);
            uint2 pkd; pkd.x = w0; pkd.y = w1;
            *(uint2*)&AO[row * C_ + h*64 + dblk*16 + lg*4] = pkd;
        }
    }
}

extern "C" void kernel_launch(void* const* d_in, const int* in_sizes, int n_in,
                              void* d_out, int out_size, void* d_ws, size_t ws_size,
                              hipStream_t stream) {
    const void* x     = d_in[0];
    const void* mask  = d_in[1];
    const void* wqkv  = d_in[2];
    const void* bqkv  = d_in[3];
    const void* wproj = d_in[4];
    const void* bproj = d_in[5];

    char* ws = (char*)d_ws;
    size_t off = 0;
    auto alloc = [&](size_t bytes) -> void* {
        void* p = ws + off;
        off = (off + bytes + 255) & ~(size_t)255;
        return p;
    };
    int* flags            = (int*)alloc(256);
    unsigned short* Xb    = (unsigned short*)alloc((size_t)BT_ * C_ * 2);
    unsigned short* WqkvT = (unsigned short*)alloc((size_t)C3_ * C_ * 2);
    unsigned short* WprojT= (unsigned short*)alloc((size_t)C_ * C_ * 2);
    float* bqkvF          = (float*)alloc((size_t)C3_ * 4);
    float* bprojF         = (float*)alloc((size_t)C_ * 4);
    float* maskF          = (float*)alloc((size_t)BT_ * 4);
    unsigned short* Qs    = (unsigned short*)alloc((size_t)B_*H_*T_*D_ * 2);
    unsigned short* Ks    = (unsigned short*)alloc((size_t)B_*H_*T_*D_ * 2);
    unsigned short* Vts   = (unsigned short*)alloc((size_t)B_*H_*T_*D_ * 2);
    unsigned short* AO    = (unsigned short*)alloc((size_t)BT_ * C_ * 2);

    k_detect<<<1, 256, 0, stream>>>(x, wqkv, bqkv, wproj, bproj, mask, flags);
    k_canon_x<<<(BT_*C_/8 + 255)/256, 256, 0, stream>>>(x, Xb, flags);
    k_canon_wT<<<dim3(C3_/32, C_/32), 256, 0, stream>>>(wqkv, WqkvT, flags, 1, C_, C3_);
    k_canon_wT<<<dim3(C_/32, C_/32), 256, 0, stream>>>(wproj, WprojT, flags, 3, C_, C_);
    k_canon_small<<<(BT_ + 255)/256, 256, 0, stream>>>(bqkv, bproj, mask, bqkvF, bprojF, maskF, flags);

    // QKV projection -> Q(,K)(,V^T)
    k_gemm<0><<<dim3(C3_/128, BT_/128), 256, 0, stream>>>(
        Xb, WqkvT, bqkvF, Qs, Ks, Vts, BT_, C3_, C_);
    // flash attention (swapped QK^T)
    k_attn<<<B_*H_*(T_/128), 256, 0, stream>>>(Qs, Ks, Vts, maskF, AO);
    // output projection -> f32 d_out
    k_gemm<1><<<dim3(C_/128, BT_/128), 256, 0, stream>>>(
        AO, WprojT, bprojF, d_out, nullptr, nullptr, BT_, C_, C_);
}

// Round 6
// 193.589 us; speedup vs baseline: 37.6855x; 1.1133x over previous
//
#include <hip/hip_runtime.h>
#include <stdint.h>

#define B_ 4
#define T_ 2048
#define C_ 768
#define H_ 12
#define D_ 64
#define BT_ (B_*T_)
#define C3_ (3*C_)
#define FMIN_ (-3.402823466e38f)
// 0.125 * log2(e): Q prescale so QK^T scores are in log2 units
#define QSCALE_ (0.18033688f)

typedef __attribute__((ext_vector_type(8))) short short8;
typedef __attribute__((ext_vector_type(4))) short s16x4;
typedef __attribute__((ext_vector_type(4))) float f32x4;

__device__ __forceinline__ float bf2f(unsigned short u) {
    union { unsigned int i; float f; } v; v.i = ((unsigned int)u) << 16; return v.f;
}
__device__ __forceinline__ unsigned short f2bf(float f) {
    union { float ff; unsigned int i; } v; v.ff = f;
    unsigned int r = v.i + 0x7fffu + ((v.i >> 16) & 1u);
    return (unsigned short)(r >> 16);
}
// packed f32x2 -> bf16x2 (RNE), single HW instr
__device__ __forceinline__ unsigned int cvtpk(float lo, float hi) {
    unsigned int r;
    asm("v_cvt_pk_bf16_f32 %0, %1, %2" : "=v"(r) : "v"(lo), "v"(hi));
    return r;
}
__device__ __forceinline__ float ldf(const void* p, size_t i, int isbf) {
    return isbf ? bf2f(((const unsigned short*)p)[i]) : ((const float*)p)[i];
}

// ---------------- dtype detection, per tensor ----------------
// flags[0..4]: 1 if {x,wqkv,bqkv,wproj,bproj} is bf16, 0 if f32
// flags[5]: mask mode: 1=int32, 2=f32, 0=uint8/bool
__global__ void k_detect(const void* x, const void* wqkv, const void* bqkv,
                         const void* wproj, const void* bproj, const void* mask,
                         int* flags) {
    __shared__ int cnt[8];
    int tid = threadIdx.x;
    if (tid < 8) cnt[tid] = 0;
    __syncthreads();
    const void* ptrs[5] = {x, wqkv, bqkv, wproj, bproj};
#pragma unroll
    for (int t = 0; t < 5; ++t) {
        unsigned short u = ((const unsigned short*)ptrs[t])[2 * tid];
        int e = (u >> 7) & 0xff;
        if (e >= 100 && e <= 140) atomicAdd(&cnt[t], 1);
    }
    if (tid < 64) {
        unsigned int d = ((const unsigned int*)mask)[tid];
        if (d <= 1u) atomicAdd(&cnt[5], 1);
        if (d == 0u || d == 0x3f800000u) atomicAdd(&cnt[6], 1);
    }
    __syncthreads();
    if (tid < 5) flags[tid] = (cnt[tid] >= 128) ? 1 : 0;
    if (tid == 5) flags[5] = (cnt[5] == 64) ? 1 : ((cnt[6] == 64) ? 2 : 0);
}

// ---------------- canonicalize x -> bf16 ----------------
__global__ void k_canon_x(const void* x, unsigned short* xb, const int* flags) {
    const int n8 = BT_ * C_ / 8;
    int i = blockIdx.x * blockDim.x + threadIdx.x;
    if (i >= n8) return;
    if (flags[0]) {
        ((int4*)xb)[i] = ((const int4*)x)[i];
    } else {
        const float4* xf = (const float4*)x;
        float4 a = xf[2*i], b = xf[2*i+1];
        short8 o;
        o[0]=(short)f2bf(a.x); o[1]=(short)f2bf(a.y); o[2]=(short)f2bf(a.z); o[3]=(short)f2bf(a.w);
        o[4]=(short)f2bf(b.x); o[5]=(short)f2bf(b.y); o[6]=(short)f2bf(b.z); o[7]=(short)f2bf(b.w);
        *(short8*)&xb[8*i] = o;
    }
}

// ---------------- transpose weight [K][N] -> bf16 [N][K] ----------------
__global__ void k_canon_wT(const void* src, unsigned short* dst, const int* flags,
                           int fidx, int K, int N) {
    __shared__ float tile[32][33];
    int mode = flags[fidx];
    int n0 = blockIdx.x * 32, k0 = blockIdx.y * 32;
    int tx = threadIdx.x & 31, ty = threadIdx.x >> 5;
    for (int r = ty; r < 32; r += 8) {
        size_t idx = (size_t)(k0 + r) * N + (n0 + tx);
        tile[r][tx] = mode ? bf2f(((const unsigned short*)src)[idx])
                           : ((const float*)src)[idx];
    }
    __syncthreads();
    for (int r = ty; r < 32; r += 8) {
        dst[(size_t)(n0 + r) * K + k0 + tx] = f2bf(tile[tx][r]);
    }
}

// ---------------- biases (f32) + mask bias ----------------
__global__ void k_canon_small(const void* bqkv, const void* bproj, const void* mask,
                              float* bqkvF, float* bprojF, float* maskF, const int* flags) {
    int i = blockIdx.x * blockDim.x + threadIdx.x;
    if (i < C3_) bqkvF[i] = ldf(bqkv, i, flags[2]);
    if (i < C_)  bprojF[i] = ldf(bproj, i, flags[4]);
    if (i < BT_) {
        int mm = flags[5];
        int mv;
        if (mm == 1)      mv = ((const int*)mask)[i] != 0;
        else if (mm == 2) mv = ((const float*)mask)[i] != 0.0f;
        else              mv = ((const unsigned char*)mask)[i] != 0;
        maskF[i] = mv ? FMIN_ : 0.0f;
    }
}

// ---------------- bf16 MFMA GEMM: C = A[M][K] * Bt[N][K]^T + bias ----------------
// EPI 0: scatter into Q([B,H,T,D], *QSCALE), K([B,H,T,D]), V^T([B,H,D,T]), bf16
// EPI 1: f32 [M][N] into d_out
template<int EPI>
__global__ __launch_bounds__(256) void k_gemm(
        const unsigned short* __restrict__ A, const unsigned short* __restrict__ Bt,
        const float* __restrict__ bias,
        void* __restrict__ out0, unsigned short* __restrict__ out1,
        unsigned short* __restrict__ out2,
        int M, int N, int K) {
    __shared__ __align__(16) unsigned short la[128*72];
    __shared__ __align__(16) unsigned short lb[128*72];
    const int tid = threadIdx.x;
    const int w = tid >> 6, lane = tid & 63, lr = lane & 15, lg = lane >> 4;
    const int wm = (w >> 1) * 64, wn = (w & 1) * 64;
    const int n0 = blockIdx.x * 128, m0 = blockIdx.y * 128;
    f32x4 acc[4][4] = {};
    for (int k0 = 0; k0 < K; k0 += 64) {
#pragma unroll
        for (int c = 0; c < 4; ++c) {
            int idx = tid + c * 256;
            int row = idx >> 3, c8 = (idx & 7) * 8;
            *(short8*)&la[row*72 + c8] = *(const short8*)&A[(size_t)(m0+row)*K + k0 + c8];
            *(short8*)&lb[row*72 + c8] = *(const short8*)&Bt[(size_t)(n0+row)*K + k0 + c8];
        }
        __syncthreads();
#pragma unroll
        for (int ks = 0; ks < 64; ks += 32) {
            short8 af[4], bfr[4];
#pragma unroll
            for (int i = 0; i < 4; ++i)
                af[i] = *(const short8*)&la[(wm + i*16 + lr)*72 + ks + lg*8];
#pragma unroll
            for (int j = 0; j < 4; ++j)
                bfr[j] = *(const short8*)&lb[(wn + j*16 + lr)*72 + ks + lg*8];
#pragma unroll
            for (int i = 0; i < 4; ++i)
#pragma unroll
                for (int j = 0; j < 4; ++j)
                    acc[i][j] = __builtin_amdgcn_mfma_f32_16x16x32_bf16(af[i], bfr[j], acc[i][j], 0, 0, 0);
        }
        __syncthreads();
    }
#pragma unroll
    for (int i = 0; i < 4; ++i)
#pragma unroll
        for (int j = 0; j < 4; ++j)
#pragma unroll
            for (int r = 0; r < 4; ++r) {
                int row = m0 + wm + i*16 + lg*4 + r;
                int col = n0 + wn + j*16 + lr;
                float v = acc[i][j][r] + bias[col];
                if (EPI == 0) {
                    int seg = col / C_;
                    int c = col - seg * C_;
                    int h = c >> 6, d = c & 63;
                    int b = row >> 11, t = row & (T_ - 1);
                    if (seg == 0)      ((unsigned short*)out0)[(((size_t)b*H_ + h)*T_ + t)*D_ + d] = f2bf(v * QSCALE_);
                    else if (seg == 1) out1[(((size_t)b*H_ + h)*T_ + t)*D_ + d] = f2bf(v);
                    else               out2[(((size_t)b*H_ + h)*D_ + d)*T_ + t] = f2bf(v);
                } else {
                    ((float*)out0)[(size_t)row * N + col] = v;
                }
            }
}

// ---------------- flash attention, swapped QK^T, log2-domain softmax ----------------
// Q[B,H,T,D] (pre-scaled by 0.125*log2e), K[B,H,T,D], V^T[B,H,D,T], all bf16.
// Block = 4 waves; wave owns 32 q rows. KVBLK = 64.
// S^T = mfma(A=K, B=Q) with C initialized to the per-key mask bias (0 / -FLT_MAX):
//   lane (lr,lg) reg r holds S[q=qc*16+lr][key=kf*16+lg*4+r], mask pre-added free.
// Softmax in log2 domain (exp = 1x v_exp_f32); defer-max THR=8 (p <= 2^8).
// PV slot-relabeled contraction (P packs in-lane via cvt_pk; V 2x ds_read_b64).
// O accumulates transposed: O^T[d][q], col=q=lr -> rescale lane-uniform.
__global__ __launch_bounds__(256) void k_attn(
        const unsigned short* __restrict__ Q, const unsigned short* __restrict__ Kt,
        const unsigned short* __restrict__ Vt, const float* __restrict__ maskF,
        unsigned short* __restrict__ AO) {
    __shared__ __align__(16) unsigned short lk[64*72];
    __shared__ __align__(16) unsigned short lv[64*72];
    __shared__ __align__(16) float lmb[64];
    const int tid = threadIdx.x;
    const int w = tid >> 6, lane = tid & 63, lr = lane & 15, lg = lane >> 4;
    // bijective XCD swizzle: 768 blocks = 8 XCD x 96; 16 consecutive share one bh's K/V
    const int per = gridDim.x >> 3;
    const int swz = (blockIdx.x & 7) * per + (blockIdx.x >> 3);
    const int bh = swz >> 4, qt = swz & 15;
    const int b = bh / H_, h = bh - b * H_;
    const int qbase = qt * 128 + w * 32;
    const unsigned short* Qb = Q  + (size_t)bh * T_ * D_;
    const unsigned short* Kb = Kt + (size_t)bh * T_ * D_;
    const unsigned short* Vb = Vt + (size_t)bh * D_ * T_;

    // Q as B-operand: lane holds col q=qc*16+lr, k-elems d = dh*32+lg*8..+7
    short8 qf[2][2];
#pragma unroll
    for (int qc = 0; qc < 2; ++qc)
#pragma unroll
        for (int dh = 0; dh < 2; ++dh)
            qf[qc][dh] = *(const short8*)&Qb[(size_t)(qbase + qc*16 + lr) * D_ + dh*32 + lg*8];

    f32x4 ot[4][2] = {};           // O^T[dblk][qc]
    float m[2] = {-INFINITY, -INFINITY}, l[2] = {0.0f, 0.0f};

    for (int kt = 0; kt < T_; kt += 64) {
#pragma unroll
        for (int c = 0; c < 2; ++c) {
            int idx = tid + c * 256;
            int row = idx >> 3, c8 = (idx & 7) * 8;
            *(short8*)&lk[row*72 + c8] = *(const short8*)&Kb[(size_t)(kt + row)*D_ + c8];
            *(short8*)&lv[row*72 + c8] = *(const short8*)&Vb[(size_t)row * T_ + kt + c8];
        }
        if (tid < 64) lmb[tid] = maskF[b*T_ + kt + tid];
        __syncthreads();

        // C-init = mask bias per key (shared by both qc); mask add is free+exact
        f32x4 st[4][2];
#pragma unroll
        for (int kf = 0; kf < 4; ++kf) {
            f32x4 mi = *(const f32x4*)&lmb[kf*16 + lg*4];
            st[kf][0] = mi;
            st[kf][1] = mi;
        }
        // S^T = K Q^T + mask
#pragma unroll
        for (int dh = 0; dh < 2; ++dh) {
            short8 kfr[4];
#pragma unroll
            for (int kf = 0; kf < 4; ++kf)
                kfr[kf] = *(const short8*)&lk[(kf*16 + lr)*72 + dh*32 + lg*8];
#pragma unroll
            for (int kf = 0; kf < 4; ++kf)
#pragma unroll
                for (int qc = 0; qc < 2; ++qc)
                    st[kf][qc] = __builtin_amdgcn_mfma_f32_16x16x32_bf16(kfr[kf], qf[qc][dh], st[kf][qc], 0, 0, 0);
        }
        // online softmax per qc (row = q = qc*16+lr; spread over 4 lanes lg)
#pragma unroll
        for (int qc = 0; qc < 2; ++qc) {
            // in-lane max over 16 (max3 trees), then reduce across lg
            float t0 = fmaxf(fmaxf(st[0][qc][0], st[0][qc][1]), st[0][qc][2]);
            float t1 = fmaxf(fmaxf(st[0][qc][3], st[1][qc][0]), st[1][qc][1]);
            float t2 = fmaxf(fmaxf(st[1][qc][2], st[1][qc][3]), st[2][qc][0]);
            float t3 = fmaxf(fmaxf(st[2][qc][1], st[2][qc][2]), st[2][qc][3]);
            float t4 = fmaxf(fmaxf(st[3][qc][0], st[3][qc][1]), st[3][qc][2]);
            float tm = fmaxf(fmaxf(t0, t1), fmaxf(fmaxf(t2, t3), fmaxf(t4, st[3][qc][3])));
            tm = fmaxf(tm, __shfl_xor(tm, 16));
            tm = fmaxf(tm, __shfl_xor(tm, 32));
            // defer-max: skip rescale while max growth <= 8 (p bounded by 2^8)
            if (!__all(tm - m[qc] <= 8.0f)) {
                float mn = fmaxf(m[qc], tm);
                float sc = __builtin_amdgcn_exp2f(m[qc] - mn);
                m[qc] = mn;
                l[qc] *= sc;
#pragma unroll
                for (int dblk = 0; dblk < 4; ++dblk) ot[dblk][qc] *= sc;
            }
            float mr = m[qc];
            float ps = 0.0f;
#pragma unroll
            for (int kf = 0; kf < 4; ++kf)
#pragma unroll
                for (int r = 0; r < 4; ++r) {
                    float p = __builtin_amdgcn_exp2f(st[kf][qc][r] - mr);
                    st[kf][qc][r] = p;
                    ps += p;
                }
            l[qc] += ps;
        }
        // pack P in-lane into relabeled B-fragments: pb[qc][ks]
        union PU { unsigned int u[4]; short8 s; };
        PU pb[2][2];
#pragma unroll
        for (int qc = 0; qc < 2; ++qc)
#pragma unroll
            for (int ks = 0; ks < 2; ++ks) {
                pb[qc][ks].u[0] = cvtpk(st[2*ks][qc][0],   st[2*ks][qc][1]);
                pb[qc][ks].u[1] = cvtpk(st[2*ks][qc][2],   st[2*ks][qc][3]);
                pb[qc][ks].u[2] = cvtpk(st[2*ks+1][qc][0], st[2*ks+1][qc][1]);
                pb[qc][ks].u[3] = cvtpk(st[2*ks+1][qc][2], st[2*ks+1][qc][3]);
            }
        // O^T += V^T P^T with matching slot relabel: A-slot (ks,j):
        //   j=0..3 -> key 32ks+lg*4+j ; j=4..7 -> key 32ks+16+lg*4+(j-4)
#pragma unroll
        for (int ks = 0; ks < 2; ++ks)
#pragma unroll
            for (int dblk = 0; dblk < 4; ++dblk) {
                const int rb = (dblk*16 + lr)*72 + 32*ks + lg*4;
                s16x4 lo = *(const s16x4*)&lv[rb];
                s16x4 hi = *(const s16x4*)&lv[rb + 16];
                short8 va;
                va[0]=lo[0]; va[1]=lo[1]; va[2]=lo[2]; va[3]=lo[3];
                va[4]=hi[0]; va[5]=hi[1]; va[6]=hi[2]; va[7]=hi[3];
#pragma unroll
                for (int qc = 0; qc < 2; ++qc)
                    ot[dblk][qc] = __builtin_amdgcn_mfma_f32_16x16x32_bf16(va, pb[qc][ks].s, ot[dblk][qc], 0, 0, 0);
            }
        __syncthreads();
    }
    // epilogue: reduce l across lg, normalize, store O^T -> AO rows
#pragma unroll
    for (int qc = 0; qc < 2; ++qc) {
        float ls = l[qc];
        ls += __shfl_xor(ls, 16);
        ls += __shfl_xor(ls, 32);
        float inv = 1.0f / ls;
        size_t row = (size_t)b*T_ + qbase + qc*16 + lr;
#pragma unroll
        for (int dblk = 0; dblk < 4; ++dblk) {
            unsigned int w0 = cvtpk(ot[dblk][qc][0]*inv, ot[dblk][qc][1]*inv);
            unsigned int w1 = cvtpk(ot[dblk][qc][2]*inv, ot[dblk][qc][3]*inv);
            uint2 pkd; pkd.x = w0; pkd.y = w1;
            *(uint2*)&AO[row * C_ + h*64 + dblk*16 + lg*4] = pkd;
        }
    }
}

extern "C" void kernel_launch(void* const* d_in, const int* in_sizes, int n_in,
                              void* d_out, int out_size, void* d_ws, size_t ws_size,
                              hipStream_t stream) {
    const void* x     = d_in[0];
    const void* mask  = d_in[1];
    const void* wqkv  = d_in[2];
    const void* bqkv  = d_in[3];
    const void* wproj = d_in[4];
    const void* bproj = d_in[5];

    char* ws = (char*)d_ws;
    size_t off = 0;
    auto alloc = [&](size_t bytes) -> void* {
        void* p = ws + off;
        off = (off + bytes + 255) & ~(size_t)255;
        return p;
    };
    int* flags            = (int*)alloc(256);
    unsigned short* Xb    = (unsigned short*)alloc((size_t)BT_ * C_ * 2);
    unsigned short* WqkvT = (unsigned short*)alloc((size_t)C3_ * C_ * 2);
    unsigned short* WprojT= (unsigned short*)alloc((size_t)C_ * C_ * 2);
    float* bqkvF          = (float*)alloc((size_t)C3_ * 4);
    float* bprojF         = (float*)alloc((size_t)C_ * 4);
    float* maskF          = (float*)alloc((size_t)BT_ * 4);
    unsigned short* Qs    = (unsigned short*)alloc((size_t)B_*H_*T_*D_ * 2);
    unsigned short* Ks    = (unsigned short*)alloc((size_t)B_*H_*T_*D_ * 2);
    unsigned short* Vts   = (unsigned short*)alloc((size_t)B_*H_*T_*D_ * 2);
    unsigned short* AO    = (unsigned short*)alloc((size_t)BT_ * C_ * 2);

    k_detect<<<1, 256, 0, stream>>>(x, wqkv, bqkv, wproj, bproj, mask, flags);
    k_canon_x<<<(BT_*C_/8 + 255)/256, 256, 0, stream>>>(x, Xb, flags);
    k_canon_wT<<<dim3(C3_/32, C_/32), 256, 0, stream>>>(wqkv, WqkvT, flags, 1, C_, C3_);
    k_canon_wT<<<dim3(C_/32, C_/32), 256, 0, stream>>>(wproj, WprojT, flags, 3, C_, C_);
    k_canon_small<<<(BT_ + 255)/256, 256, 0, stream>>>(bqkv, bproj, mask, bqkvF, bprojF, maskF, flags);

    // QKV projection -> Q(,K)(,V^T)
    k_gemm<0><<<dim3(C3_/128, BT_/128), 256, 0, stream>>>(
        Xb, WqkvT, bqkvF, Qs, Ks, Vts, BT_, C3_, C_);
    // flash attention (swapped QK^T, log2-domain softmax)
    k_attn<<<B_*H_*(T_/128), 256, 0, stream>>>(Qs, Ks, Vts, maskF, AO);
    // output projection -> f32 d_out
    k_gemm<1><<<dim3(C_/128, BT_/128), 256, 0, stream>>>(
        AO, WprojT, bprojF, d_out, nullptr, nullptr, BT_, C_, C_);
}